// Round 1
// baseline (103.202 us; speedup 1.0000x reference)
//
#include <hip/hip_runtime.h>
#include <math.h>

#define NQ 4
#define DIM 16
#define K 512

// ---------------------------------------------------------------------------
// Kernel 1: per-wave row GEMM.  pre_out[b][q] = dot(x[b], w[q]) + bias[q]
// One wave (64 lanes) per batch row; lanes split K=512 as 2x float4 each.
// ---------------------------------------------------------------------------
__global__ __launch_bounds__(256) void qnet_gemm(const float* __restrict__ x,
                                                 const float* __restrict__ w,
                                                 const float* __restrict__ bias,
                                                 float* __restrict__ pre_out,
                                                 int B) {
    int wave = (int)((blockIdx.x * blockDim.x + threadIdx.x) >> 6);
    int lane = (int)(threadIdx.x & 63);
    if (wave >= B) return;

    const float* xr = x + (size_t)wave * K;
    // Coalesced: first load covers [0,1024) bytes across the wave, second [1024,2048)
    float4 x0 = *(const float4*)(xr + lane * 4);
    float4 x1 = *(const float4*)(xr + 256 + lane * 4);

    float acc[NQ];
#pragma unroll
    for (int q = 0; q < NQ; ++q) {
        const float* wr = w + q * K;
        float4 w0 = *(const float4*)(wr + lane * 4);
        float4 w1 = *(const float4*)(wr + 256 + lane * 4);
        acc[q] = x0.x * w0.x + x0.y * w0.y + x0.z * w0.z + x0.w * w0.w
               + x1.x * w1.x + x1.y * w1.y + x1.z * w1.z + x1.w * w1.w;
    }

#pragma unroll
    for (int off = 32; off >= 1; off >>= 1) {
#pragma unroll
        for (int q = 0; q < NQ; ++q)
            acc[q] += __shfl_xor(acc[q], off, 64);
    }

    if (lane == 0) {
        float4 r = make_float4(acc[0] + bias[0], acc[1] + bias[1],
                               acc[2] + bias[2], acc[3] + bias[3]);
        *(float4*)(pre_out + (size_t)wave * 4) = r;
    }
}

// ---------------------------------------------------------------------------
// Kernel 2: one thread per batch row. 4-qubit statevector (16 complex amps)
// entirely in registers; all loops fully unrolled (compile-time indices).
// Qubit q maps to bit (3-q) of the amplitude index (q=0 is MSB).
// ---------------------------------------------------------------------------
__global__ __launch_bounds__(64) void qnet_circuit(const float* __restrict__ pre_out,
                                                   const float* __restrict__ u3p,
                                                   const float* __restrict__ post_w,
                                                   const float* __restrict__ post_b,
                                                   float* __restrict__ out,
                                                   int B) {
    int b = (int)(blockIdx.x * blockDim.x + threadIdx.x);
    if (b >= B) return;

    float4 p4 = *(const float4*)(pre_out + (size_t)b * 4);
    float pre[NQ] = {p4.x, p4.y, p4.z, p4.w};

    float ry[NQ], rz[NQ];
#pragma unroll
    for (int q = 0; q < NQ; ++q) {
        float qi = tanhf(pre[q] * 0.1f) * 1.5707963267948966f;
        ry[q] = atanf(qi);
        rz[q] = atanf(qi * qi);
    }

    // After H on all 4 qubits of |0000>, state is uniformly 1/4 (real).
    float sr[DIM], si[DIM];
#pragma unroll
    for (int i = 0; i < DIM; ++i) { sr[i] = 0.25f; si[i] = 0.0f; }

    // RY(theta): [[c,-s],[s,c]] with c=cos(theta/2), s=sin(theta/2) (real gate)
#pragma unroll
    for (int q = 0; q < NQ; ++q) {
        float c, s;
        __sincosf(ry[q] * 0.5f, &s, &c);
        const int m = 1 << (3 - q);
#pragma unroll
        for (int i = 0; i < DIM; ++i) {
            if (i & m) continue;
            const int j = i | m;
            float r0 = sr[i], i0 = si[i], r1 = sr[j], i1 = si[j];
            sr[i] = c * r0 - s * r1;  si[i] = c * i0 - s * i1;
            sr[j] = s * r0 + c * r1;  si[j] = s * i0 + c * i1;
        }
    }

    // RZ(theta): diag(e^{-i t/2}, e^{+i t/2})
#pragma unroll
    for (int q = 0; q < NQ; ++q) {
        float c, s;
        __sincosf(rz[q] * 0.5f, &s, &c);
        const int m = 1 << (3 - q);
#pragma unroll
        for (int i = 0; i < DIM; ++i) {
            const float sg = (i & m) ? s : -s;   // multiply by (c, sg)
            float r = sr[i], im = si[i];
            sr[i] = c * r - sg * im;
            si[i] = c * im + sg * r;
        }
    }

    // CNOT ring step=1 then step=2, applied sequentially.
    const int cn_c[8] = {0, 1, 2, 3, 0, 1, 2, 3};
    const int cn_t[8] = {1, 2, 3, 0, 2, 3, 0, 1};
#pragma unroll
    for (int k = 0; k < 8; ++k) {
        const int cm = 1 << (3 - cn_c[k]);
        const int tm = 1 << (3 - cn_t[k]);
#pragma unroll
        for (int i = 0; i < DIM; ++i) {
            if ((i & cm) && !(i & tm)) {
                const int j = i | tm;
                float tr = sr[i]; sr[i] = sr[j]; sr[j] = tr;
                float ti = si[i]; si[i] = si[j]; si[j] = ti;
            }
        }
    }

    // U3(th,ph,la) = [[ct, -e^{i la} st], [e^{i ph} st, e^{i(ph+la)} ct]]
#pragma unroll
    for (int q = 0; q < NQ; ++q) {
        float th = u3p[q * 3 + 0], ph = u3p[q * 3 + 1], la = u3p[q * 3 + 2];
        float ct, st, cl, sl, cp, sp, cpl, spl;
        __sincosf(th * 0.5f, &st, &ct);
        __sincosf(la, &sl, &cl);
        __sincosf(ph, &sp, &cp);
        __sincosf(ph + la, &spl, &cpl);
        const float g01r = -cl * st, g01i = -sl * st;
        const float g10r = cp * st,  g10i = sp * st;
        const float g11r = cpl * ct, g11i = spl * ct;
        const int m = 1 << (3 - q);
#pragma unroll
        for (int i = 0; i < DIM; ++i) {
            if (i & m) continue;
            const int j = i | m;
            float r0 = sr[i], i0 = si[i], r1 = sr[j], i1 = si[j];
            sr[i] = ct * r0 + g01r * r1 - g01i * i1;
            si[i] = ct * i0 + g01r * i1 + g01i * r1;
            sr[j] = g10r * r0 - g10i * i0 + g11r * r1 - g11i * i1;
            si[j] = g10r * i0 + g10i * r0 + g11r * i1 + g11i * r1;
        }
    }

    // Z expectation per qubit: sum_{idx} |amp|^2 * (bit(3-q) ? -1 : +1)
    float ex[NQ] = {0.f, 0.f, 0.f, 0.f};
#pragma unroll
    for (int i = 0; i < DIM; ++i) {
        const float p2 = sr[i] * sr[i] + si[i] * si[i];
#pragma unroll
        for (int q = 0; q < NQ; ++q)
            ex[q] += (i & (1 << (3 - q))) ? -p2 : p2;
    }

    float o0 = post_b[0], o1 = post_b[1];
#pragma unroll
    for (int q = 0; q < NQ; ++q) {
        o0 += ex[q] * post_w[q];       // post_w row 0
        o1 += ex[q] * post_w[4 + q];   // post_w row 1
    }
    *(float2*)(out + (size_t)b * 2) = make_float2(o0, o1);
}

extern "C" void kernel_launch(void* const* d_in, const int* in_sizes, int n_in,
                              void* d_out, int out_size, void* d_ws, size_t ws_size,
                              hipStream_t stream) {
    const float* x      = (const float*)d_in[0];  // [B, 512]
    const float* pre_w  = (const float*)d_in[1];  // [4, 512]
    const float* pre_b  = (const float*)d_in[2];  // [4]
    const float* u3p    = (const float*)d_in[3];  // [4, 3]
    const float* post_w = (const float*)d_in[4];  // [2, 4]
    const float* post_b = (const float*)d_in[5];  // [2]
    float* out = (float*)d_out;                   // [B, 2]

    const int B = in_sizes[0] / K;                // 32768
    float* pre_out = (float*)d_ws;                // [B, 4] scratch

    // Kernel 1: one wave per row; 4 waves per block.
    {
        int waves_per_block = 4;
        int blocks = (B + waves_per_block - 1) / waves_per_block;
        qnet_gemm<<<blocks, waves_per_block * 64, 0, stream>>>(x, pre_w, pre_b, pre_out, B);
    }
    // Kernel 2: one thread per row.
    {
        int threads = 64;
        int blocks = (B + threads - 1) / threads;
        qnet_circuit<<<blocks, threads, 0, stream>>>(pre_out, u3p, post_w, post_b, out, B);
    }
}